// Round 10
// baseline (268.078 us; speedup 1.0000x reference)
//
#include <hip/hip_runtime.h>

#define HW 512
#define NPIX (HW * HW)        // 262144 pixels
#define LDS_PIX 163840        // 160 KB u8 slice in LDS (62.5% of table)
#define THREADS 1024          // 16 waves/block, 1 block/CU (LDS-capped)
#define BLOCKS 256            // DIAGNOSTIC: 1 block per CU, 2x work per CU ->
                              // whdr ~135us -> surfaces in rocprof top-5 with
                              // counters for the BEST-known config (R5).
#define NB 4                  // elems per round
#define RNDS 8                // 4*8 = 32 elems/thread; 256*1024*32 = 8388608 = N

// Reference constants
#define EPS_F  1e-10f
constexpr double B_d  = 1.0 + 0.1 + 0.05;        // 1.15
constexpr double BR_d = 1.0 + 0.1 - 0.05;        // 1.05
#define B_F    ((float)B_d)
#define INVB_F ((float)(1.0 / B_d))
#define BR_F   ((float)BR_d)
#define BL_F   ((float)(1.0 / BR_d))

typedef __attribute__((ext_vector_type(4))) int ivec4;

// u8 table: k = round(m*255), v = (k+1)/256. |dv| <= 1/512; measured final
// absmax 1.95e-3 vs threshold 7.07e-3.
__global__ void build_v(const float* __restrict__ vin,
                        unsigned char* __restrict__ vq,
                        float* __restrict__ out) {
    int i = blockIdx.x * blockDim.x + threadIdx.x;
    if (i == 0) *out = 0.0f;                     // fold d_out zero-init here
    if (i < NPIX) {
        float s = vin[i] + vin[i + NPIX] + vin[i + 2 * NPIX];
        float m = s * (1.0f / 3.0f);
        vq[i] = (unsigned char)__float2int_rn(m * 255.0f);
    }
}

__device__ __forceinline__ float rcp_fast(float x) {
#if __has_builtin(__builtin_amdgcn_rcpf)
    return __builtin_amdgcn_rcpf(x);             // v_rcp_f32, ~1 ulp — margin is 3.6x
#else
    return 1.0f / x;
#endif
}

__device__ __forceinline__ float per_loss(float r1, float r2, int d) {
    float ratio = r1 * rcp_fast(r2 + EPS_F);
    float rinv  = r2 * rcp_fast(r1 + EPS_F);
    float l1 = (ratio > INVB_F) ? (ratio - INVB_F + (B_F - rinv)) : 0.0f;
    float l2 = (ratio < B_F)    ? (B_F - ratio + (rinv - INVB_F)) : 0.0f;
    float l0 = (ratio > BR_F)   ? (ratio - BR_F + (BL_F - rinv))
             : ((ratio < BL_F)  ? (BL_F - ratio + (rinv - BR_F)) : 0.0f);
    return (d == 1) ? l1 : ((d == 2) ? l2 : l0);
}

// ---- pipeline building blocks (sched_barrier(0) at call sites keeps the
// issue order: the compiler may not sink loads down to their consumers) ----

__device__ __forceinline__ void load_c(ivec4 (&cc)[NB], const ivec4* __restrict__ coords,
                                       int tid, int T, int ofs) {
    #pragma unroll
    for (int k = 0; k < NB; ++k)
        cc[k] = __builtin_nontemporal_load(&coords[tid + (ofs + k) * T]);
}

__device__ __forceinline__ void load_dw(int (&dd)[NB], float (&ww)[NB],
                                        const int* __restrict__ darker,
                                        const float* __restrict__ weights,
                                        int tid, int T, int ofs) {
    #pragma unroll
    for (int k = 0; k < NB; ++k)
        dd[k] = __builtin_nontemporal_load(&darker[tid + (ofs + k) * T]);
    #pragma unroll
    for (int k = 0; k < NB; ++k)
        ww[k] = __builtin_nontemporal_load(&weights[tid + (ofs + k) * T]);
}

// Hybrid gather: 62.5% of lanes hit LDS, rest go global (table L2-resident;
// NT streams don't evict it).
__device__ __forceinline__ void gather_issue(const ivec4 (&cc)[NB],
        unsigned (&q1)[NB], unsigned (&q2)[NB],
        const unsigned char* lv, const unsigned char* __restrict__ vq) {
    #pragma unroll
    for (int k = 0; k < NB; ++k) {
        int i1 = cc[k].y * HW + cc[k].x;
        int i2 = cc[k].w * HW + cc[k].z;
        if (i1 < LDS_PIX) q1[k] = lv[i1]; else q1[k] = vq[i1];
        if (i2 < LDS_PIX) q2[k] = lv[i2]; else q2[k] = vq[i2];
    }
}

__device__ __forceinline__ void consume(const unsigned (&q1)[NB], const unsigned (&q2)[NB],
                                        const int (&dd)[NB], const float (&ww)[NB],
                                        float& acc) {
    #pragma unroll
    for (int k = 0; k < NB; ++k) {
        float r1 = (float)(q1[k] + 1) * (1.0f / 256.0f);
        float r2 = (float)(q2[k] + 1) * (1.0f / 256.0f);
        acc += ww[k] * per_loss(r1, r2, dd[k]);
    }
}

#define SBAR() __builtin_amdgcn_sched_barrier(0)

// amdgpu_waves_per_eu(4,4): pin allocator at the LDS-capped occupancy ->
// 128-VGPR budget, no spill (R5-verified: first measurable win).
__global__ __launch_bounds__(THREADS)
__attribute__((amdgpu_waves_per_eu(4, 4)))
void whdr_kernel(
        const unsigned char* __restrict__ vq,
        const ivec4* __restrict__ coords,
        const int*   __restrict__ darker,
        const float* __restrict__ weights,
        float*       __restrict__ out,
        int n) {
    __shared__ unsigned char lv[LDS_PIX];        // 160 KB -> 1 block/CU
    const int tid = blockIdx.x * THREADS + threadIdx.x;
    const int T   = BLOCKS * THREADS;            // 262144
    float acc = 0.0f;

    if (n == T * NB * RNDS) {
        // ---- steady-state: 8 rounds; streams A/B ping-pong 2 rounds ahead,
        // gathers double-buffered 1 round ahead (identical to R5's schedule) ----
        ivec4 cA[NB], cB[NB];
        int   dA[NB], dB[NB];
        float wA[NB], wB[NB];
        unsigned qA1[NB], qA2[NB], qB1[NB], qB2[NB];

        load_c (cA, coords, tid, T, 0);
        load_dw(dA, wA, darker, weights, tid, T, 0);
        load_c (cB, coords, tid, T, NB);
        load_dw(dB, wB, darker, weights, tid, T, NB);
        {   // cooperative LDS fill: 160 B/thread, 16B coalesced
            const uint4* s4 = (const uint4*)vq;
            uint4* d4 = (uint4*)lv;
            #pragma unroll
            for (int j = threadIdx.x; j < LDS_PIX / 16; j += THREADS) d4[j] = s4[j];
        }
        __syncthreads();
        gather_issue(cA, qA1, qA2, lv, vq);            SBAR();  // G0

#define RPF(r, CUR, NXT) \
        gather_issue(c##NXT, q##NXT##1, q##NXT##2, lv, vq);        SBAR(); \
        load_c (c##CUR, coords, tid, T, (r + 2) * NB);             SBAR(); \
        consume(q##CUR##1, q##CUR##2, d##CUR, w##CUR, acc); \
        load_dw(d##CUR, w##CUR, darker, weights, tid, T, (r + 2) * NB); SBAR();

        RPF(0, A, B)
        RPF(1, B, A)
        RPF(2, A, B)
        RPF(3, B, A)
        RPF(4, A, B)
        RPF(5, B, A)
#undef RPF
        // round 6: gather r7(B), consume r6(A) — no more stream prefetch
        gather_issue(cB, qB1, qB2, lv, vq);            SBAR();
        consume(qA1, qA2, dA, wA, acc);
        // round 7: drain
        consume(qB1, qB2, dB, wB, acc);
    } else {
        // ---- generic fallback (any n) ----
        {
            const uint4* s4 = (const uint4*)vq;
            uint4* d4 = (uint4*)lv;
            for (int j = threadIdx.x; j < LDS_PIX / 16; j += THREADS) d4[j] = s4[j];
        }
        __syncthreads();
        const int TT = gridDim.x * THREADS;
        for (int i = tid; i < n; i += TT) {
            ivec4 c = coords[i];
            int i1 = c.y * HW + c.x, i2 = c.w * HW + c.z;
            unsigned a = (i1 < LDS_PIX) ? (unsigned)lv[i1] : (unsigned)vq[i1];
            unsigned b = (i2 < LDS_PIX) ? (unsigned)lv[i2] : (unsigned)vq[i2];
            float r1 = (float)(a + 1) * (1.0f / 256.0f);
            float r2 = (float)(b + 1) * (1.0f / 256.0f);
            acc += weights[i] * per_loss(r1, r2, darker[i]);
        }
    }

    // wave-64 shuffle reduction
    #pragma unroll
    for (int off = 32; off > 0; off >>= 1)
        acc += __shfl_down(acc, off, 64);
    // Reuse lv's LDS for the block reduction (table reads done; barrier
    // orders the reuse).
    __syncthreads();
    float* wsum = (float*)lv;
    int lane = threadIdx.x & 63;
    int wid  = threadIdx.x >> 6;                 // 16 waves
    if (lane == 0) wsum[wid] = acc;
    __syncthreads();
    if (threadIdx.x == 0) {
        float s = 0.0f;
        #pragma unroll
        for (int i = 0; i < THREADS / 64; ++i) s += wsum[i];
        atomicAdd(out, s / (float)n);            // n = 2^23 -> exact
    }
}

extern "C" void kernel_launch(void* const* d_in, const int* in_sizes, int n_in,
                              void* d_out, int out_size, void* d_ws, size_t ws_size,
                              hipStream_t stream) {
    const float* v_input = (const float*)d_in[0];  // (3,512,512) f32
    const ivec4* coords  = (const ivec4*)d_in[1];  // (N,4) i32
    const int*   darker  = (const int*)d_in[2];    // (N,) i32
    const float* weights = (const float*)d_in[3];  // (N,) f32
    float* out = (float*)d_out;
    unsigned char* vq = (unsigned char*)d_ws;      // 256 KB u8 v table
    int n = in_sizes[2];                           // N

    build_v<<<(NPIX + 255) / 256, 256, 0, stream>>>(v_input, vq, out);
    whdr_kernel<<<BLOCKS, THREADS, 0, stream>>>(vq, coords, darker, weights, out, n);
}

// Round 11
// 266.477 us; speedup vs baseline: 1.0060x; 1.0060x over previous
//
#include <hip/hip_runtime.h>

#define HW 512
#define NPIX (HW * HW)        // 262144 pixels
#define LDS_PIX 163840        // 160 KB u8 slice in LDS (62.5% of table)
#define THREADS 1024          // 16 waves/block, 1 block/CU (LDS-capped)
#define BLOCKS 256            // persistent: 1 block per CU, fill LDS once
#define NB 2                  // elems per round — SIZED TO THE 64-VGPR BUDGET
#define RNDS 16               // 2*16 = 32 elems/thread; 256*1024*32 = 8388608 = N

// Reference constants
#define EPS_F  1e-10f
constexpr double B_d  = 1.0 + 0.1 + 0.05;        // 1.15
constexpr double BR_d = 1.0 + 0.1 - 0.05;        // 1.05
#define B_F    ((float)B_d)
#define INVB_F ((float)(1.0 / B_d))
#define BR_F   ((float)BR_d)
#define BL_F   ((float)(1.0 / BR_d))

typedef __attribute__((ext_vector_type(4))) int ivec4;

// u8 table: k = round(m*255), v = (k+1)/256. |dv| <= 1/512; measured final
// absmax 1.95e-3 vs threshold 7.07e-3.
__global__ void build_v(const float* __restrict__ vin,
                        unsigned char* __restrict__ vq,
                        float* __restrict__ out) {
    int i = blockIdx.x * blockDim.x + threadIdx.x;
    if (i == 0) *out = 0.0f;                     // fold d_out zero-init here
    if (i < NPIX) {
        float s = vin[i] + vin[i + NPIX] + vin[i + 2 * NPIX];
        float m = s * (1.0f / 3.0f);
        vq[i] = (unsigned char)__float2int_rn(m * 255.0f);
    }
}

__device__ __forceinline__ float rcp_fast(float x) {
#if __has_builtin(__builtin_amdgcn_rcpf)
    return __builtin_amdgcn_rcpf(x);             // v_rcp_f32, ~1 ulp — margin is 3.6x
#else
    return 1.0f / x;
#endif
}

__device__ __forceinline__ float per_loss(float r1, float r2, int d) {
    float ratio = r1 * rcp_fast(r2 + EPS_F);
    float rinv  = r2 * rcp_fast(r1 + EPS_F);
    float l1 = (ratio > INVB_F) ? (ratio - INVB_F + (B_F - rinv)) : 0.0f;
    float l2 = (ratio < B_F)    ? (B_F - ratio + (rinv - INVB_F)) : 0.0f;
    float l0 = (ratio > BR_F)   ? (ratio - BR_F + (BL_F - rinv))
             : ((ratio < BL_F)  ? (BL_F - ratio + (rinv - BR_F)) : 0.0f);
    return (d == 1) ? l1 : ((d == 2) ? l2 : l0);
}

// ---- pipeline building blocks (sched_barrier(0) at call sites keeps the
// issue order: the compiler may not sink loads down to their consumers) ----

__device__ __forceinline__ void load_c(ivec4 (&cc)[NB], const ivec4* __restrict__ coords,
                                       int tid, int T, int ofs) {
    #pragma unroll
    for (int k = 0; k < NB; ++k)
        cc[k] = __builtin_nontemporal_load(&coords[tid + (ofs + k) * T]);
}

__device__ __forceinline__ void load_dw(int (&dd)[NB], float (&ww)[NB],
                                        const int* __restrict__ darker,
                                        const float* __restrict__ weights,
                                        int tid, int T, int ofs) {
    #pragma unroll
    for (int k = 0; k < NB; ++k)
        dd[k] = __builtin_nontemporal_load(&darker[tid + (ofs + k) * T]);
    #pragma unroll
    for (int k = 0; k < NB; ++k)
        ww[k] = __builtin_nontemporal_load(&weights[tid + (ofs + k) * T]);
}

// Hybrid gather: 62.5% of lanes hit LDS, rest go global (table L2/L3-resident;
// NT streams don't evict it).
__device__ __forceinline__ void gather_issue(const ivec4 (&cc)[NB],
        unsigned (&q1)[NB], unsigned (&q2)[NB],
        const unsigned char* lv, const unsigned char* __restrict__ vq) {
    #pragma unroll
    for (int k = 0; k < NB; ++k) {
        int i1 = cc[k].y * HW + cc[k].x;
        int i2 = cc[k].w * HW + cc[k].z;
        if (i1 < LDS_PIX) q1[k] = lv[i1]; else q1[k] = vq[i1];
        if (i2 < LDS_PIX) q2[k] = lv[i2]; else q2[k] = vq[i2];
    }
}

__device__ __forceinline__ void consume(const unsigned (&q1)[NB], const unsigned (&q2)[NB],
                                        const int (&dd)[NB], const float (&ww)[NB],
                                        float& acc) {
    #pragma unroll
    for (int k = 0; k < NB; ++k) {
        float r1 = (float)(q1[k] + 1) * (1.0f / 256.0f);
        float r2 = (float)(q2[k] + 1) * (1.0f / 256.0f);
        acc += ww[k] * per_loss(r1, r2, dd[k]);
    }
}

#define SBAR() __builtin_amdgcn_sched_barrier(0)

// R10 counters proved: 1024-thread blocks get a HARD 64-VGPR budget (both
// launch_bounds(1024,4) and amdgpu_waves_per_eu(4,4) are inert — VGPR_Count
// stayed 64) and NB=4 pipeline state (~80-90 live regs) spills ~40 dwords/
// thread to scratch (WRITE_SIZE 39.9 MB), round-tripped inside the dep chain.
// Fix: design INTO the budget. NB=2 state: c 16 + dw 8 + q 8 + temps ~15
// = ~47 regs -> no spill, same R5 schedule (gathers 1 round ahead, streams
// 2 ahead). Persistent 256-block grid fills LDS exactly once per CU.
__global__ __launch_bounds__(THREADS)
void whdr_kernel(
        const unsigned char* __restrict__ vq,
        const ivec4* __restrict__ coords,
        const int*   __restrict__ darker,
        const float* __restrict__ weights,
        float*       __restrict__ out,
        int n) {
    __shared__ unsigned char lv[LDS_PIX];        // 160 KB -> 1 block/CU
    const int tid = blockIdx.x * THREADS + threadIdx.x;
    const int T   = BLOCKS * THREADS;            // 262144
    float acc = 0.0f;

    if (n == T * NB * RNDS) {
        // ---- steady-state: 16 rounds; streams A/B ping-pong 2 rounds ahead,
        // gathers double-buffered 1 round ahead ----
        ivec4 cA[NB], cB[NB];
        int   dA[NB], dB[NB];
        float wA[NB], wB[NB];
        unsigned qA1[NB], qA2[NB], qB1[NB], qB2[NB];

        load_c (cA, coords, tid, T, 0);
        load_dw(dA, wA, darker, weights, tid, T, 0);
        load_c (cB, coords, tid, T, NB);
        load_dw(dB, wB, darker, weights, tid, T, NB);
        {   // cooperative LDS fill: 160 B/thread, 16B coalesced
            const uint4* s4 = (const uint4*)vq;
            uint4* d4 = (uint4*)lv;
            #pragma unroll
            for (int j = threadIdx.x; j < LDS_PIX / 16; j += THREADS) d4[j] = s4[j];
        }
        __syncthreads();
        gather_issue(cA, qA1, qA2, lv, vq);            SBAR();  // G0

#define RPF(r, CUR, NXT) \
        gather_issue(c##NXT, q##NXT##1, q##NXT##2, lv, vq);        SBAR(); \
        load_c (c##CUR, coords, tid, T, (r + 2) * NB);             SBAR(); \
        consume(q##CUR##1, q##CUR##2, d##CUR, w##CUR, acc); \
        load_dw(d##CUR, w##CUR, darker, weights, tid, T, (r + 2) * NB); SBAR();

        RPF(0, A, B)
        RPF(1, B, A)
        RPF(2, A, B)
        RPF(3, B, A)
        RPF(4, A, B)
        RPF(5, B, A)
        RPF(6, A, B)
        RPF(7, B, A)
        RPF(8, A, B)
        RPF(9, B, A)
        RPF(10, A, B)
        RPF(11, B, A)
        RPF(12, A, B)
        RPF(13, B, A)
#undef RPF
        // round 14: gather r15(B), consume r14(A) — no more stream prefetch
        gather_issue(cB, qB1, qB2, lv, vq);            SBAR();
        consume(qA1, qA2, dA, wA, acc);
        // round 15: drain
        consume(qB1, qB2, dB, wB, acc);
    } else {
        // ---- generic fallback (any n) ----
        {
            const uint4* s4 = (const uint4*)vq;
            uint4* d4 = (uint4*)lv;
            for (int j = threadIdx.x; j < LDS_PIX / 16; j += THREADS) d4[j] = s4[j];
        }
        __syncthreads();
        const int TT = gridDim.x * THREADS;
        for (int i = tid; i < n; i += TT) {
            ivec4 c = coords[i];
            int i1 = c.y * HW + c.x, i2 = c.w * HW + c.z;
            unsigned a = (i1 < LDS_PIX) ? (unsigned)lv[i1] : (unsigned)vq[i1];
            unsigned b = (i2 < LDS_PIX) ? (unsigned)lv[i2] : (unsigned)vq[i2];
            float r1 = (float)(a + 1) * (1.0f / 256.0f);
            float r2 = (float)(b + 1) * (1.0f / 256.0f);
            acc += weights[i] * per_loss(r1, r2, darker[i]);
        }
    }

    // wave-64 shuffle reduction
    #pragma unroll
    for (int off = 32; off > 0; off >>= 1)
        acc += __shfl_down(acc, off, 64);
    // Reuse lv's LDS for the block reduction (table reads done; barrier
    // orders the reuse).
    __syncthreads();
    float* wsum = (float*)lv;
    int lane = threadIdx.x & 63;
    int wid  = threadIdx.x >> 6;                 // 16 waves
    if (lane == 0) wsum[wid] = acc;
    __syncthreads();
    if (threadIdx.x == 0) {
        float s = 0.0f;
        #pragma unroll
        for (int i = 0; i < THREADS / 64; ++i) s += wsum[i];
        atomicAdd(out, s / (float)n);            // n = 2^23 -> exact
    }
}

extern "C" void kernel_launch(void* const* d_in, const int* in_sizes, int n_in,
                              void* d_out, int out_size, void* d_ws, size_t ws_size,
                              hipStream_t stream) {
    const float* v_input = (const float*)d_in[0];  // (3,512,512) f32
    const ivec4* coords  = (const ivec4*)d_in[1];  // (N,4) i32
    const int*   darker  = (const int*)d_in[2];    // (N,) i32
    const float* weights = (const float*)d_in[3];  // (N,) f32
    float* out = (float*)d_out;
    unsigned char* vq = (unsigned char*)d_ws;      // 256 KB u8 v table
    int n = in_sizes[2];                           // N

    build_v<<<(NPIX + 255) / 256, 256, 0, stream>>>(v_input, vq, out);
    whdr_kernel<<<BLOCKS, THREADS, 0, stream>>>(vq, coords, darker, weights, out, n);
}

// Round 13
// 247.224 us; speedup vs baseline: 1.0844x; 1.0779x over previous
//
#include <hip/hip_runtime.h>

#define HW 512
#define NPIX (HW * HW)        // 262144 pixels
#define LDS_PIX 163840        // 160 KB u8 slice in LDS (62.5% of table)
#define THREADS 1024          // 16 waves/block, 1 block/CU resident (LDS-capped)
#define BLOCKS 1024           // 4 sequential blocks/CU: maximize burst-prologue
                              // episodes (R5 512blk=68us vs R10/R11 256blk=85us:
                              // block boundaries are worth ~16us)
#define NB 2                  // elems per round (state ~45 regs < 64 budget)
#define RNDS 4                // 2*4 = 8 elems/thread; 1024*1024*8 = 8388608 = N

// Reference constants
#define EPS_F  1e-10f
constexpr double B_d  = 1.0 + 0.1 + 0.05;        // 1.15
constexpr double BR_d = 1.0 + 0.1 - 0.05;        // 1.05
#define B_F    ((float)B_d)
#define INVB_F ((float)(1.0 / B_d))
#define BR_F   ((float)BR_d)
#define BL_F   ((float)(1.0 / BR_d))

typedef __attribute__((ext_vector_type(4))) int ivec4;

// u8 table: k = round(m*255), v = (k+1)/256. |dv| <= 1/512; measured final
// absmax 1.95e-3 vs threshold 7.07e-3.
__global__ void build_v(const float* __restrict__ vin,
                        unsigned char* __restrict__ vq,
                        float* __restrict__ out) {
    int i = blockIdx.x * blockDim.x + threadIdx.x;
    if (i == 0) *out = 0.0f;                     // fold d_out zero-init here
    if (i < NPIX) {
        float s = vin[i] + vin[i + NPIX] + vin[i + 2 * NPIX];
        float m = s * (1.0f / 3.0f);
        vq[i] = (unsigned char)__float2int_rn(m * 255.0f);
    }
}

__device__ __forceinline__ float rcp_fast(float x) {
#if __has_builtin(__builtin_amdgcn_rcpf)
    return __builtin_amdgcn_rcpf(x);             // v_rcp_f32, ~1 ulp — margin is 3.6x
#else
    return 1.0f / x;
#endif
}

__device__ __forceinline__ float per_loss(float r1, float r2, int d) {
    float ratio = r1 * rcp_fast(r2 + EPS_F);
    float rinv  = r2 * rcp_fast(r1 + EPS_F);
    float l1 = (ratio > INVB_F) ? (ratio - INVB_F + (B_F - rinv)) : 0.0f;
    float l2 = (ratio < B_F)    ? (B_F - ratio + (rinv - INVB_F)) : 0.0f;
    float l0 = (ratio > BR_F)   ? (ratio - BR_F + (BL_F - rinv))
             : ((ratio < BL_F)  ? (BL_F - ratio + (rinv - BR_F)) : 0.0f);
    return (d == 1) ? l1 : ((d == 2) ? l2 : l0);
}

// ---- pipeline building blocks (sched_barrier(0) at call sites keeps the
// issue order: the compiler may not sink loads down to their consumers) ----

__device__ __forceinline__ void load_c(ivec4 (&cc)[NB], const ivec4* __restrict__ coords,
                                       int tid, int T, int ofs) {
    #pragma unroll
    for (int k = 0; k < NB; ++k)
        cc[k] = __builtin_nontemporal_load(&coords[tid + (ofs + k) * T]);
}

__device__ __forceinline__ void load_dw(int (&dd)[NB], float (&ww)[NB],
                                        const int* __restrict__ darker,
                                        const float* __restrict__ weights,
                                        int tid, int T, int ofs) {
    #pragma unroll
    for (int k = 0; k < NB; ++k)
        dd[k] = __builtin_nontemporal_load(&darker[tid + (ofs + k) * T]);
    #pragma unroll
    for (int k = 0; k < NB; ++k)
        ww[k] = __builtin_nontemporal_load(&weights[tid + (ofs + k) * T]);
}

// Hybrid gather: 62.5% of lanes hit LDS, rest go global (table L2/L3-resident;
// NT streams don't evict it).
__device__ __forceinline__ void gather_issue(const ivec4 (&cc)[NB],
        unsigned (&q1)[NB], unsigned (&q2)[NB],
        const unsigned char* lv, const unsigned char* __restrict__ vq) {
    #pragma unroll
    for (int k = 0; k < NB; ++k) {
        int i1 = cc[k].y * HW + cc[k].x;
        int i2 = cc[k].w * HW + cc[k].z;
        if (i1 < LDS_PIX) q1[k] = lv[i1]; else q1[k] = vq[i1];
        if (i2 < LDS_PIX) q2[k] = lv[i2]; else q2[k] = vq[i2];
    }
}

__device__ __forceinline__ void consume(const unsigned (&q1)[NB], const unsigned (&q2)[NB],
                                        const int (&dd)[NB], const float (&ww)[NB],
                                        float& acc) {
    #pragma unroll
    for (int k = 0; k < NB; ++k) {
        float r1 = (float)(q1[k] + 1) * (1.0f / 256.0f);
        float r2 = (float)(q2[k] + 1) * (1.0f / 256.0f);
        acc += ww[k] * per_loss(r1, r2, dd[k]);
    }
}

#define SBAR() __builtin_amdgcn_sched_barrier(0)

// WRITE_SIZE lesson (R10 vs R11): the ~39 MB "writes" on this kernel are L3
// writeback of the harness's 512 MB poison fill (evicted by our stream
// fetches), NOT scratch — NB=4 and NB=2 showed identical WRITE_SIZE. The
// genuine spills were R2 (big pipeline state) and R4/R7 (32-reg budget at
// 256-thr blocks). NB=2 at 1024-thr (64-reg budget) is spill-free.
__global__ __launch_bounds__(THREADS)
__attribute__((amdgpu_waves_per_eu(4, 4)))
void whdr_kernel(
        const unsigned char* __restrict__ vq,
        const ivec4* __restrict__ coords,
        const int*   __restrict__ darker,
        const float* __restrict__ weights,
        float*       __restrict__ out,
        int n) {
    __shared__ unsigned char lv[LDS_PIX];        // 160 KB -> 1 block/CU
    const int tid = blockIdx.x * THREADS + threadIdx.x;
    const int T   = BLOCKS * THREADS;            // 1048576
    float acc = 0.0f;

    if (n == T * NB * RNDS) {
        // ---- steady-state: burst-prologue + 4 short rounds ----
        ivec4 cA[NB], cB[NB];
        int   dA[NB], dB[NB];
        float wA[NB], wB[NB];
        unsigned qA1[NB], qA2[NB], qB1[NB], qB2[NB];

        // Prologue burst: 12 independent stream loads, then LDS fill —
        // all in flight together (the deep-MLP phase that makes more
        // block boundaries a win).
        load_c (cA, coords, tid, T, 0);
        load_dw(dA, wA, darker, weights, tid, T, 0);
        load_c (cB, coords, tid, T, NB);
        load_dw(dB, wB, darker, weights, tid, T, NB);
        {   // cooperative LDS fill: 160 B/thread, 16B coalesced
            const uint4* s4 = (const uint4*)vq;
            uint4* d4 = (uint4*)lv;
            #pragma unroll
            for (int j = threadIdx.x; j < LDS_PIX / 16; j += THREADS) d4[j] = s4[j];
        }
        __syncthreads();
        gather_issue(cA, qA1, qA2, lv, vq);            SBAR();  // G0

#define RPF(r, CUR, NXT) \
        gather_issue(c##NXT, q##NXT##1, q##NXT##2, lv, vq);        SBAR(); \
        load_c (c##CUR, coords, tid, T, (r + 2) * NB);             SBAR(); \
        consume(q##CUR##1, q##CUR##2, d##CUR, w##CUR, acc); \
        load_dw(d##CUR, w##CUR, darker, weights, tid, T, (r + 2) * NB); SBAR();

        RPF(0, A, B)   // consume r0(A); gather r1(B); stream r2 -> A
        RPF(1, B, A)   // consume r1(B); gather r2(A); stream r3 -> B
#undef RPF
        // round 2: gather r3(B), consume r2(A) — no more stream prefetch
        gather_issue(cB, qB1, qB2, lv, vq);            SBAR();
        consume(qA1, qA2, dA, wA, acc);
        // round 3: drain
        consume(qB1, qB2, dB, wB, acc);
    } else {
        // ---- generic fallback (any n) ----
        {
            const uint4* s4 = (const uint4*)vq;
            uint4* d4 = (uint4*)lv;
            for (int j = threadIdx.x; j < LDS_PIX / 16; j += THREADS) d4[j] = s4[j];
        }
        __syncthreads();
        const int TT = gridDim.x * THREADS;
        for (int i = tid; i < n; i += TT) {
            ivec4 c = coords[i];
            int i1 = c.y * HW + c.x, i2 = c.w * HW + c.z;
            unsigned a = (i1 < LDS_PIX) ? (unsigned)lv[i1] : (unsigned)vq[i1];
            unsigned b = (i2 < LDS_PIX) ? (unsigned)lv[i2] : (unsigned)vq[i2];
            float r1 = (float)(a + 1) * (1.0f / 256.0f);
            float r2 = (float)(b + 1) * (1.0f / 256.0f);
            acc += weights[i] * per_loss(r1, r2, darker[i]);
        }
    }

    // wave-64 shuffle reduction
    #pragma unroll
    for (int off = 32; off > 0; off >>= 1)
        acc += __shfl_down(acc, off, 64);
    // Reuse lv's LDS for the block reduction (table reads done; barrier
    // orders the reuse).
    __syncthreads();
    float* wsum = (float*)lv;
    int lane = threadIdx.x & 63;
    int wid  = threadIdx.x >> 6;                 // 16 waves
    if (lane == 0) wsum[wid] = acc;
    __syncthreads();
    if (threadIdx.x == 0) {
        float s = 0.0f;
        #pragma unroll
        for (int i = 0; i < THREADS / 64; ++i) s += wsum[i];
        atomicAdd(out, s / (float)n);            // n = 2^23 -> exact
    }
}

extern "C" void kernel_launch(void* const* d_in, const int* in_sizes, int n_in,
                              void* d_out, int out_size, void* d_ws, size_t ws_size,
                              hipStream_t stream) {
    const float* v_input = (const float*)d_in[0];  // (3,512,512) f32
    const ivec4* coords  = (const ivec4*)d_in[1];  // (N,4) i32
    const int*   darker  = (const int*)d_in[2];    // (N,) i32
    const float* weights = (const float*)d_in[3];  // (N,) f32
    float* out = (float*)d_out;
    unsigned char* vq = (unsigned char*)d_ws;      // 256 KB u8 v table
    int n = in_sizes[2];                           // N

    build_v<<<(NPIX + 255) / 256, 256, 0, stream>>>(v_input, vq, out);
    whdr_kernel<<<BLOCKS, THREADS, 0, stream>>>(vq, coords, darker, weights, out, n);
}